// Round 12
// baseline (164.542 us; speedup 1.0000x reference)
//
#include <hip/hip_runtime.h>
#include <hip/hip_bf16.h>
#include <math.h>

#define D_MODEL 1024
#define NHEAD 16
#define DHEAD 64
#define SEQ 2048
#define BATCH 2
#define MTOT (BATCH * SEQ)  // 4096

typedef __attribute__((ext_vector_type(8))) short bf16x8;   // 4 VGPRs = MFMA A/B frag
typedef __attribute__((ext_vector_type(4))) float f32x4;    // MFMA C/D frag

static __device__ __forceinline__ ushort f2b(float x) {
  __hip_bfloat16 h = __float2bfloat16(x);
  union { __hip_bfloat16 h; ushort u; } cv; cv.h = h; return cv.u;
}

// async global->LDS, 16B per lane (m97). LDS dest = wave-uniform base + lane*16.
#define GLLDS16(gp, lp)                                                     \
  __builtin_amdgcn_global_load_lds(                                         \
      (const __attribute__((address_space(1))) unsigned int*)(gp),          \
      (__attribute__((address_space(3))) unsigned int*)(lp), 16, 0, 0)

// 0.125 (1/sqrt(Dh)) * log2(e): folded into Q at projection; flash exp2's raw scores
#define QSCALE 0.18033688011112042f

// ---------------------------------------------------------------------------
// prep: fp32->bf16 for X + 4 weights, plus RoPE cos/sin table. (unchanged)
// ---------------------------------------------------------------------------
__global__ __launch_bounds__(256)
void prep(const float* __restrict__ X, const float* __restrict__ Wq,
          const float* __restrict__ Wk, const float* __restrict__ Wv,
          const float* __restrict__ Wo, ushort* __restrict__ Xb,
          ushort* __restrict__ Wqb, ushort* __restrict__ Wkb,
          ushort* __restrict__ Wvb, ushort* __restrict__ Wob,
          float2* __restrict__ tbl) {
  int bid = blockIdx.x;
  if (bid >= 8192) {  // rope table: idx = s*32 + i
    int idx = (bid - 8192) * 256 + threadIdx.x;
    int s = idx >> 5, i = idx & 31;
    float inv = exp2f((float)i * -0.4152410118609203f);  // 10000^(-i/32)
    float sn, cs;
    sincosf((float)s * inv, &sn, &cs);
    tbl[idx] = make_float2(cs, sn);
    return;
  }
  const float* in;
  ushort* out;
  int i;
  if (bid < 4096) {
    in = X; out = Xb; i = bid * 256 + threadIdx.x;
  } else {
    int ws = (bid - 4096) >> 10;
    in = (ws == 0) ? Wq : (ws == 1) ? Wk : (ws == 2) ? Wv : Wo;
    out = (ws == 0) ? Wqb : (ws == 1) ? Wkb : (ws == 2) ? Wvb : Wob;
    i = ((bid - 4096) & 1023) * 256 + threadIdx.x;
  }
  float4 v = ((const float4*)in)[i];
  ushort4 o;
  o.x = f2b(v.x); o.y = f2b(v.y); o.z = f2b(v.z); o.w = f2b(v.w);
  ((ushort4*)out)[i] = o;
}

// ---------------------------------------------------------------------------
// bf16 MFMA GEMM: out = A @ W^T. m97 structure with BK=64 (R5 proven win).
// QKV launch: M=128 tile, 768 blocks = 3 blocks/CU. R10 measured the M=64
// variant (6 blocks/CU) SLOWER (45.7 vs ~40 us): FETCH 38->71 MB -- the
// doubled W-panel reads miss the per-XCD L2, and 3/CU co-residency already
// hides the vmcnt drains (m114). M=128 is the verified optimum for QKV.
// mode 1 (QKV): RoPE-by-table on Q/K (+QSCALE on Q); V written transposed
// (B,H,Dh,S) with KEY-PERMUTED columns pos(s) = 32*(s>>5) + ((s>>2)&3)*8 +
// ((s>>4)&1)*4 + (s&3) -- matches the MFMA k-slot order of flash's S^T
// C-regs, so flash feeds P^T into the PV MFMA straight from registers.
// mode 0: fp32 row-major store (final output).
// ---------------------------------------------------------------------------
__global__ __launch_bounds__(256)
void gemm_bf16(const ushort* __restrict__ A,
               const ushort* __restrict__ W0, const ushort* __restrict__ W1,
               const ushort* __restrict__ W2,
               const float2* __restrict__ tbl,
               float* __restrict__ outF,
               ushort* __restrict__ o0, ushort* __restrict__ o1,
               ushort* __restrict__ o2, int mode) {
  __shared__ ushort As[128 * 64];   // 16 KB, chunk-swizzled (flash geometry)
  __shared__ ushort Bs[128 * 64];   // 16 KB
  const int tid = threadIdx.x;
  const int lane = tid & 63;
  const int w = tid >> 6;
  const int quad = lane >> 4, l15 = lane & 15;
  const int wy = w >> 1, wx = w & 1;
  const int m0 = blockIdx.y * 128, n0 = blockIdx.x * 128;
  const int z = blockIdx.z;
  const ushort* W = (z == 0) ? W0 : (z == 1) ? W1 : W2;
  ushort* outB = (z == 0) ? o0 : (z == 1) ? o1 : o2;

  // staging: thread owns rows rl+32k (k=0..3), LDS slot tid&7, chunk XOR'd.
  const int rl = tid >> 3;                // 0..31
  const int gsc = (tid & 7) ^ (rl & 7);   // pre-swizzled global chunk
  const ushort* Ag = A + (size_t)(m0 + rl) * D_MODEL + gsc * 8;
  const ushort* Wg = W + (size_t)(n0 + rl) * D_MODEL + gsc * 8;

  // reader chunk slot: frag (row, chunk = 4*kk+quad) at slot (4kk+quad)^(row&7)
  const int s0 = (quad ^ (l15 & 7)) * 8;  // kk=0; kk=1 is ^32 (ushorts)

  f32x4 acc[4][4];
#pragma unroll
  for (int i = 0; i < 4; ++i)
#pragma unroll
    for (int j = 0; j < 4; ++j) acc[i][j] = (f32x4){0.f, 0.f, 0.f, 0.f};

  for (int kt = 0; kt < D_MODEL / 64; ++kt) {
    if (kt) __syncthreads();
#pragma unroll
    for (int k4 = 0; k4 < 4; ++k4) {
      GLLDS16(Ag + kt * 64 + (size_t)(k4 * 32) * D_MODEL,
              &As[(size_t)tid * 8 + k4 * 2048]);
      GLLDS16(Wg + kt * 64 + (size_t)(k4 * 32) * D_MODEL,
              &Bs[(size_t)tid * 8 + k4 * 2048]);
    }
    __syncthreads();  // compiler drains vmcnt before barrier (1 per 64 K)

#pragma unroll
    for (int kk = 0; kk < 2; ++kk) {
      const int sk = s0 ^ (kk * 32);
      bf16x8 af[4], bfr[4];
#pragma unroll
      for (int mt = 0; mt < 4; ++mt) {
        int row = wy * 64 + mt * 16 + l15;
        af[mt] = *(const bf16x8*)&As[row * 64 + sk];
      }
#pragma unroll
      for (int nt = 0; nt < 4; ++nt) {
        int row = wx * 64 + nt * 16 + l15;
        bfr[nt] = *(const bf16x8*)&Bs[row * 64 + sk];
      }
#pragma unroll
      for (int mt = 0; mt < 4; ++mt)
#pragma unroll
        for (int nt = 0; nt < 4; ++nt)
          acc[mt][nt] = __builtin_amdgcn_mfma_f32_16x16x32_bf16(
              af[mt], bfr[nt], acc[mt][nt], 0, 0, 0);
    }
  }

  // ---- epilogue. C/D: row = quad*4+r, col = l15 per 16x16 tile.
  const float qsc = (z == 0) ? QSCALE : 1.0f;
#pragma unroll
  for (int mt = 0; mt < 4; ++mt) {
    int m_base = m0 + wy * 64 + mt * 16 + quad * 4;
    int b = m_base >> 11, s_base = m_base & (SEQ - 1);
#pragma unroll
    for (int nt = 0; nt < 4; ++nt) {
      int n = n0 + wx * 64 + nt * 16 + l15;
      if (mode == 0) {
#pragma unroll
        for (int r = 0; r < 4; ++r)
          outF[(size_t)(m_base + r) * D_MODEL + n] = acc[mt][nt][r];
      } else {
        int h = n >> 6, dh = n & 63;
        if (z == 2) {  // V: transposed + key-permuted columns (see header)
          int p_base = (s_base & ~31) | (((s_base >> 2) & 3) << 3) |
                       (((s_base >> 4) & 1) << 2);
          ushort4 o;
          o.x = f2b(acc[mt][nt][0]); o.y = f2b(acc[mt][nt][1]);
          o.z = f2b(acc[mt][nt][2]); o.w = f2b(acc[mt][nt][3]);
          *(ushort4*)&outB[((size_t)(b * NHEAD + h) * DHEAD + dh) * SEQ + p_base] = o;
        } else {       // Q/K: RoPE via table, pair partner via lane shuffle
          int i = nt * 8 + (l15 >> 1);   // freq index, pair-uniform
          bool evn = !(l15 & 1);
#pragma unroll
          for (int r = 0; r < 4; ++r) {
            float v = acc[mt][nt][r];
            float pv = __shfl_xor(v, 1);
            float2 csn = tbl[(s_base + r) * 32 + i];
            v = v * csn.x + (evn ? -pv * csn.y : pv * csn.y);
            v *= qsc;
            outB[(((size_t)(b * NHEAD + h)) * SEQ + s_base + r) * DHEAD + dh] = f2b(v);
          }
        }
      }
    }
  }
}

// ---------------------------------------------------------------------------
// gemm_out: Wo projection, M=64 / BK=64 skeleton (R9 proven win: 512 blocks
// = 2 blocks/CU hides the vmcnt-drain barriers that the 1-block/CU M=128
// launch exposed; 166.0 -> 163.5 us). UNCHANGED.
// out = A @ W^T, fp32 row-major store.
// ---------------------------------------------------------------------------
__global__ __launch_bounds__(256)
void gemm_out(const ushort* __restrict__ A, const ushort* __restrict__ W,
              float* __restrict__ outF) {
  __shared__ ushort As[64 * 64];    // 8 KB
  __shared__ ushort Bs[128 * 64];   // 16 KB
  const int tid = threadIdx.x;
  const int lane = tid & 63;
  const int w = tid >> 6;           // wave owns col group w*32
  const int quad = lane >> 4, l15 = lane & 15;
  const int m0 = blockIdx.y * 64, n0 = blockIdx.x * 128;

  const int rl = tid >> 3;                // 0..31
  const int gsc = (tid & 7) ^ (rl & 7);   // pre-swizzled global chunk
  const ushort* Ag = A + (size_t)(m0 + rl) * D_MODEL + gsc * 8;
  const ushort* Wg = W + (size_t)(n0 + rl) * D_MODEL + gsc * 8;

  const int s0 = (quad ^ (l15 & 7)) * 8;  // kk=0; kk=1 is ^32 (ushorts)

  f32x4 acc[4][2];
#pragma unroll
  for (int i = 0; i < 4; ++i)
#pragma unroll
    for (int j = 0; j < 2; ++j) acc[i][j] = (f32x4){0.f, 0.f, 0.f, 0.f};

  for (int kt = 0; kt < D_MODEL / 64; ++kt) {
    if (kt) __syncthreads();
#pragma unroll
    for (int k4 = 0; k4 < 2; ++k4)   // A: 64 rows = 2 row-groups
      GLLDS16(Ag + kt * 64 + (size_t)(k4 * 32) * D_MODEL,
              &As[(size_t)tid * 8 + k4 * 2048]);
#pragma unroll
    for (int k4 = 0; k4 < 4; ++k4)   // W: 128 rows = 4 row-groups
      GLLDS16(Wg + kt * 64 + (size_t)(k4 * 32) * D_MODEL,
              &Bs[(size_t)tid * 8 + k4 * 2048]);
    __syncthreads();

#pragma unroll
    for (int kk = 0; kk < 2; ++kk) {
      const int sk = s0 ^ (kk * 32);
      bf16x8 af[4], bfr[2];
#pragma unroll
      for (int mt = 0; mt < 4; ++mt) {
        int row = mt * 16 + l15;
        af[mt] = *(const bf16x8*)&As[row * 64 + sk];
      }
#pragma unroll
      for (int nt = 0; nt < 2; ++nt) {
        int row = w * 32 + nt * 16 + l15;
        bfr[nt] = *(const bf16x8*)&Bs[row * 64 + sk];
      }
#pragma unroll
      for (int mt = 0; mt < 4; ++mt)
#pragma unroll
        for (int nt = 0; nt < 2; ++nt)
          acc[mt][nt] = __builtin_amdgcn_mfma_f32_16x16x32_bf16(
              af[mt], bfr[nt], acc[mt][nt], 0, 0, 0);
    }
  }

  // ---- epilogue: fp32 row-major. C/D: row = quad*4+r, col = l15.
#pragma unroll
  for (int mt = 0; mt < 4; ++mt) {
    int m_base = m0 + mt * 16 + quad * 4;
#pragma unroll
    for (int nt = 0; nt < 2; ++nt) {
      int n = n0 + w * 32 + nt * 16 + l15;
#pragma unroll
      for (int r = 0; r < 4; ++r)
        outF[(size_t)(m_base + r) * D_MODEL + n] = acc[mt][nt][r];
    }
  }
}

// ---------------------------------------------------------------------------
// bf16 MFMA causal flash attention -- R0 PROVEN FORM + isolated T5 setprio.
// Structure unchanged (survived R2/R4/R6/R7 perturbations). This round's
// SINGLE variable: s_setprio(1)/(0) around the two MFMA clusters only.
// Mechanism (m191): 4 independent blocks/CU at different kt phases -- the
// CU scheduler prefers the block in its MFMA section over blocks doing LDS
// writes/exp2. (R6 bundled setprio with a sync restructure; its isolated
// sign on this kernel was never measured. Pre-committed read: total >= 163
// => negative, revert and converge.)
// S^T = K.Q^T via mfma(A=K, B=Q): qrow in l15, keys in quad*4+r; exp2'd
// P packed to bf16 in registers feeds O^T = V^T.P^T directly (key-permuted
// Vt columns baked by the QKV gemm). Unpadded XOR LDS geometry
// (conflicts=0); register-prefetch staging; per-lane scalar row sums.
// Heads 8-15 walk qt reversed for CU balance. 1024 blocks, 4/CU, 16KB LDS.
// ---------------------------------------------------------------------------
__global__ __launch_bounds__(256)
void flash_mfma(const ushort* __restrict__ Q, const ushort* __restrict__ K,
                const ushort* __restrict__ Vt, ushort* __restrict__ O) {
  __shared__ ushort Ks[64 * 64];     // [key][dh], chunk-swizzled
  __shared__ ushort Vs[64 * 64];     // [dh][keypos], chunk-swizzled
  const int tid = threadIdx.x;
  const int lane = tid & 63, w = tid >> 6;
  const int quad = lane >> 4, l15 = lane & 15;
  const int h = blockIdx.y, b = blockIdx.z;
  const int qt = (h >= 8) ? (31 - blockIdx.x) : blockIdx.x;
  const int bh = b * NHEAD + h;

  // Q as B-operand (B frag layout == A frag layout): lane n=l15=qrow
  const int qrow = qt * 64 + w * 16 + l15;
  const ushort* Qrow = Q + ((size_t)bh * SEQ + qrow) * 64;
  bf16x8 aq0 = *(const bf16x8*)(Qrow + quad * 8);
  bf16x8 aq1 = *(const bf16x8*)(Qrow + 32 + quad * 8);

  // staging: thread owns rows rl and rl+32, LDS slot tid&7, global chunk XOR'd
  const int rl = tid >> 3;
  const int gsc = (tid & 7) ^ (rl & 7);  // (rl+32)&7 == rl&7
  const ushort* Kg0 = K + ((size_t)bh * SEQ + rl) * 64 + gsc * 8;
  const ushort* Kg1 = Kg0 + (size_t)32 * 64;
  const ushort* Vg0 = Vt + ((size_t)bh * 64 + rl) * SEQ + gsc * 8;
  const ushort* Vg1 = Vg0 + (size_t)32 * SEQ;

  // reader chunk slots (slot quad^(r&7) holds chunk quad; frag rows r&7==l15&7)
  const int sA = (quad ^ (l15 & 7)) * 8;  // dh/keypos 0..31
  const int sB = sA ^ 32;                 // dh/keypos 32..63

  float rsl = 0.f;       // per-lane row sum (lane's qrow)
  f32x4 accO[4];         // O^T dh-tiles: row=dh quad*4+r, col=l15=qrow
#pragma unroll
  for (int nt = 0; nt < 4; ++nt) accO[nt] = (f32x4){0.f, 0.f, 0.f, 0.f};

  float4 pk0 = *(const float4*)(Kg0);
  float4 pk1 = *(const float4*)(Kg1);
  float4 pv0 = *(const float4*)(Vg0);
  float4 pv1 = *(const float4*)(Vg1);

  for (int kt = 0; kt <= qt; ++kt) {
    __syncthreads();  // prior iter's LDS reads complete
    *(float4*)&Ks[tid * 8]        = pk0;
    *(float4*)&Ks[2048 + tid * 8] = pk1;
    *(float4*)&Vs[tid * 8]        = pv0;
    *(float4*)&Vs[2048 + tid * 8] = pv1;
    __syncthreads();
    if (kt < qt) {  // prefetch kt+1 into registers; overlaps all compute below
      pk0 = *(const float4*)(Kg0 + (size_t)(kt + 1) * 64 * 64);
      pk1 = *(const float4*)(Kg1 + (size_t)(kt + 1) * 64 * 64);
      pv0 = *(const float4*)(Vg0 + (kt + 1) * 64);
      pv1 = *(const float4*)(Vg1 + (kt + 1) * 64);
    }

    // ---- S^T = K . Q^T : C-tile nt holds keys nt*16+quad*4+r, qrow=l15
    f32x4 sc[4];
    __builtin_amdgcn_s_setprio(1);
#pragma unroll
    for (int nt = 0; nt < 4; ++nt) {
      const ushort* kr = &Ks[(nt * 16 + l15) * 64];
      bf16x8 bk0 = *(const bf16x8*)(kr + sA);
      bf16x8 bk1 = *(const bf16x8*)(kr + sB);
      f32x4 zz = (f32x4){0.f, 0.f, 0.f, 0.f};
      zz = __builtin_amdgcn_mfma_f32_16x16x32_bf16(bk0, aq0, zz, 0, 0, 0);
      zz = __builtin_amdgcn_mfma_f32_16x16x32_bf16(bk1, aq1, zz, 0, 0, 0);
      sc[nt] = zz;
    }
    __builtin_amdgcn_s_setprio(0);

    // ---- exp2 + causal mask + row-sum + pack P^T B-frags in registers
    const bool diag = (kt == qt);
    uint pk[8];
#pragma unroll
    for (int nt = 0; nt < 4; ++nt) {
      int kbase = kt * 64 + nt * 16 + quad * 4;
      ushort us[4];
#pragma unroll
      for (int r = 0; r < 4; ++r) {
        float p = __builtin_amdgcn_exp2f(sc[nt][r]);
        if (diag && kbase + r > qrow) p = 0.f;
        rsl += p;
        us[r] = f2b(p);
      }
      pk[nt * 2]     = (uint)us[0] | ((uint)us[1] << 16);
      pk[nt * 2 + 1] = (uint)us[2] | ((uint)us[3] << 16);
    }
    union { uint u[4]; bf16x8 v; } B0, B1;
    B0.u[0] = pk[0]; B0.u[1] = pk[1]; B0.u[2] = pk[2]; B0.u[3] = pk[3];
    B1.u[0] = pk[4]; B1.u[1] = pk[5]; B1.u[2] = pk[6]; B1.u[3] = pk[7];

    // ---- O^T += V^T . P^T  (A from LDS, B straight from registers)
    __builtin_amdgcn_s_setprio(1);
#pragma unroll
    for (int nt = 0; nt < 4; ++nt) {
      const ushort* vr = &Vs[(nt * 16 + l15) * 64];
      bf16x8 av0 = *(const bf16x8*)(vr + sA);
      bf16x8 av1 = *(const bf16x8*)(vr + sB);
      accO[nt] = __builtin_amdgcn_mfma_f32_16x16x32_bf16(av0, B0.v, accO[nt], 0, 0, 0);
      accO[nt] = __builtin_amdgcn_mfma_f32_16x16x32_bf16(av1, B1.v, accO[nt], 0, 0, 0);
    }
    __builtin_amdgcn_s_setprio(0);
  }

  // ---- row-sum reduction across the 4 quads (lane's qrow fixed = l15)
  rsl += __shfl_xor(rsl, 16);
  rsl += __shfl_xor(rsl, 32);
  float invl = 1.f / rsl;

  // ---- epilogue: attn_out bf16, (B,S,H*Dh); lane writes 4 ushort4 runs
  size_t base = ((size_t)(b * SEQ + qrow)) * D_MODEL + h * 64;
#pragma unroll
  for (int nt = 0; nt < 4; ++nt) {
    ushort4 o;
    o.x = f2b(accO[nt][0] * invl);
    o.y = f2b(accO[nt][1] * invl);
    o.z = f2b(accO[nt][2] * invl);
    o.w = f2b(accO[nt][3] * invl);
    *(ushort4*)&O[base + nt * 16 + quad * 4] = o;
  }
}

// ---------------------------------------------------------------------------
extern "C" void kernel_launch(void* const* d_in, const int* in_sizes, int n_in,
                              void* d_out, int out_size, void* d_ws, size_t ws_size,
                              hipStream_t stream) {
  const float* X  = (const float*)d_in[0];
  const float* Wq = (const float*)d_in[1];
  const float* Wk = (const float*)d_in[2];
  const float* Wv = (const float*)d_in[3];
  const float* Wo = (const float*)d_in[4];
  float* out = (float*)d_out;

  ushort* Xb  = (ushort*)d_ws;
  ushort* Wqb = Xb  + (size_t)MTOT * D_MODEL;
  ushort* Wkb = Wqb + (size_t)D_MODEL * D_MODEL;
  ushort* Wvb = Wkb + (size_t)D_MODEL * D_MODEL;
  ushort* Wob = Wvb + (size_t)D_MODEL * D_MODEL;
  ushort* Qw  = Wob + (size_t)D_MODEL * D_MODEL;
  ushort* Kw  = Qw  + (size_t)MTOT * D_MODEL;
  ushort* Vtw = Kw  + (size_t)MTOT * D_MODEL;  // (B,H,Dh,S) key-permuted
  ushort* At  = Vtw + (size_t)MTOT * D_MODEL;
  float2* tbl = (float2*)(At + (size_t)MTOT * D_MODEL);  // 512 KB

  prep<<<8448, 256, 0, stream>>>(X, Wq, Wk, Wv, Wo, Xb, Wqb, Wkb, Wvb, Wob, tbl);

  // QKV projection: M=128 tile (R10: M=64 regressed via L2-miss W re-fetch);
  // RoPE fused (table) on Q/K, Q pre-scaled; V transposed+permuted
  gemm_bf16<<<dim3(D_MODEL / 128, MTOT / 128, 3), 256, 0, stream>>>(
      Xb, Wqb, Wkb, Wvb, tbl, nullptr, Qw, Kw, Vtw, 1);

  flash_mfma<<<dim3(SEQ / 64, NHEAD, BATCH), 256, 0, stream>>>(Qw, Kw, Vtw, At);

  // Wo projection: M=64 tile -> 512 blocks = 2 blocks/CU (drain-hiding)
  gemm_out<<<dim3(D_MODEL / 128, MTOT / 64), 256, 0, stream>>>(At, Wob, out);
}

// Round 13
// 161.833 us; speedup vs baseline: 1.0167x; 1.0167x over previous
//
#include <hip/hip_runtime.h>
#include <hip/hip_bf16.h>
#include <math.h>

#define D_MODEL 1024
#define NHEAD 16
#define DHEAD 64
#define SEQ 2048
#define BATCH 2
#define MTOT (BATCH * SEQ)  // 4096

typedef __attribute__((ext_vector_type(8))) short bf16x8;   // 4 VGPRs = MFMA A/B frag
typedef __attribute__((ext_vector_type(4))) float f32x4;    // MFMA C/D frag

static __device__ __forceinline__ ushort f2b(float x) {
  __hip_bfloat16 h = __float2bfloat16(x);
  union { __hip_bfloat16 h; ushort u; } cv; cv.h = h; return cv.u;
}

// async global->LDS, 16B per lane (m97). LDS dest = wave-uniform base + lane*16.
#define GLLDS16(gp, lp)                                                     \
  __builtin_amdgcn_global_load_lds(                                         \
      (const __attribute__((address_space(1))) unsigned int*)(gp),          \
      (__attribute__((address_space(3))) unsigned int*)(lp), 16, 0, 0)

// 0.125 (1/sqrt(Dh)) * log2(e): folded into Q at projection; flash exp2's raw scores
#define QSCALE 0.18033688011112042f

// ---------------------------------------------------------------------------
// prep: fp32->bf16 for X + 4 weights, plus RoPE cos/sin table.
// ---------------------------------------------------------------------------
__global__ __launch_bounds__(256)
void prep(const float* __restrict__ X, const float* __restrict__ Wq,
          const float* __restrict__ Wk, const float* __restrict__ Wv,
          const float* __restrict__ Wo, ushort* __restrict__ Xb,
          ushort* __restrict__ Wqb, ushort* __restrict__ Wkb,
          ushort* __restrict__ Wvb, ushort* __restrict__ Wob,
          float2* __restrict__ tbl) {
  int bid = blockIdx.x;
  if (bid >= 8192) {  // rope table: idx = s*32 + i
    int idx = (bid - 8192) * 256 + threadIdx.x;
    int s = idx >> 5, i = idx & 31;
    float inv = exp2f((float)i * -0.4152410118609203f);  // 10000^(-i/32)
    float sn, cs;
    sincosf((float)s * inv, &sn, &cs);
    tbl[idx] = make_float2(cs, sn);
    return;
  }
  const float* in;
  ushort* out;
  int i;
  if (bid < 4096) {
    in = X; out = Xb; i = bid * 256 + threadIdx.x;
  } else {
    int ws = (bid - 4096) >> 10;
    in = (ws == 0) ? Wq : (ws == 1) ? Wk : (ws == 2) ? Wv : Wo;
    out = (ws == 0) ? Wqb : (ws == 1) ? Wkb : (ws == 2) ? Wvb : Wob;
    i = ((bid - 4096) & 1023) * 256 + threadIdx.x;
  }
  float4 v = ((const float4*)in)[i];
  ushort4 o;
  o.x = f2b(v.x); o.y = f2b(v.y); o.z = f2b(v.z); o.w = f2b(v.w);
  ((ushort4*)out)[i] = o;
}

// ---------------------------------------------------------------------------
// bf16 MFMA GEMM: out = A @ W^T. m97 structure with BK=64 (R5 proven win).
// QKV launch: M=128 tile, 768 blocks = 3 blocks/CU. R10 measured the M=64
// variant (6 blocks/CU) SLOWER (45.7 vs ~40 us): FETCH 38->71 MB -- the
// doubled W-panel reads miss the per-XCD L2, and 3/CU co-residency already
// hides the vmcnt drains (m114). M=128 is the verified optimum for QKV.
// mode 1 (QKV): RoPE-by-table on Q/K (+QSCALE on Q); V written transposed
// (B,H,Dh,S) with KEY-PERMUTED columns pos(s) = 32*(s>>5) + ((s>>2)&3)*8 +
// ((s>>4)&1)*4 + (s&3) -- matches the MFMA k-slot order of flash's S^T
// C-regs, so flash feeds P^T into the PV MFMA straight from registers.
// mode 0: fp32 row-major store (final output).
// ---------------------------------------------------------------------------
__global__ __launch_bounds__(256)
void gemm_bf16(const ushort* __restrict__ A,
               const ushort* __restrict__ W0, const ushort* __restrict__ W1,
               const ushort* __restrict__ W2,
               const float2* __restrict__ tbl,
               float* __restrict__ outF,
               ushort* __restrict__ o0, ushort* __restrict__ o1,
               ushort* __restrict__ o2, int mode) {
  __shared__ ushort As[128 * 64];   // 16 KB, chunk-swizzled (flash geometry)
  __shared__ ushort Bs[128 * 64];   // 16 KB
  const int tid = threadIdx.x;
  const int lane = tid & 63;
  const int w = tid >> 6;
  const int quad = lane >> 4, l15 = lane & 15;
  const int wy = w >> 1, wx = w & 1;
  const int m0 = blockIdx.y * 128, n0 = blockIdx.x * 128;
  const int z = blockIdx.z;
  const ushort* W = (z == 0) ? W0 : (z == 1) ? W1 : W2;
  ushort* outB = (z == 0) ? o0 : (z == 1) ? o1 : o2;

  // staging: thread owns rows rl+32k (k=0..3), LDS slot tid&7, chunk XOR'd.
  const int rl = tid >> 3;                // 0..31
  const int gsc = (tid & 7) ^ (rl & 7);   // pre-swizzled global chunk
  const ushort* Ag = A + (size_t)(m0 + rl) * D_MODEL + gsc * 8;
  const ushort* Wg = W + (size_t)(n0 + rl) * D_MODEL + gsc * 8;

  // reader chunk slot: frag (row, chunk = 4*kk+quad) at slot (4kk+quad)^(row&7)
  const int s0 = (quad ^ (l15 & 7)) * 8;  // kk=0; kk=1 is ^32 (ushorts)

  f32x4 acc[4][4];
#pragma unroll
  for (int i = 0; i < 4; ++i)
#pragma unroll
    for (int j = 0; j < 4; ++j) acc[i][j] = (f32x4){0.f, 0.f, 0.f, 0.f};

  for (int kt = 0; kt < D_MODEL / 64; ++kt) {
    if (kt) __syncthreads();
#pragma unroll
    for (int k4 = 0; k4 < 4; ++k4) {
      GLLDS16(Ag + kt * 64 + (size_t)(k4 * 32) * D_MODEL,
              &As[(size_t)tid * 8 + k4 * 2048]);
      GLLDS16(Wg + kt * 64 + (size_t)(k4 * 32) * D_MODEL,
              &Bs[(size_t)tid * 8 + k4 * 2048]);
    }
    __syncthreads();  // compiler drains vmcnt before barrier (1 per 64 K)

#pragma unroll
    for (int kk = 0; kk < 2; ++kk) {
      const int sk = s0 ^ (kk * 32);
      bf16x8 af[4], bfr[4];
#pragma unroll
      for (int mt = 0; mt < 4; ++mt) {
        int row = wy * 64 + mt * 16 + l15;
        af[mt] = *(const bf16x8*)&As[row * 64 + sk];
      }
#pragma unroll
      for (int nt = 0; nt < 4; ++nt) {
        int row = wx * 64 + nt * 16 + l15;
        bfr[nt] = *(const bf16x8*)&Bs[row * 64 + sk];
      }
#pragma unroll
      for (int mt = 0; mt < 4; ++mt)
#pragma unroll
        for (int nt = 0; nt < 4; ++nt)
          acc[mt][nt] = __builtin_amdgcn_mfma_f32_16x16x32_bf16(
              af[mt], bfr[nt], acc[mt][nt], 0, 0, 0);
    }
  }

  // ---- epilogue. C/D: row = quad*4+r, col = l15 per 16x16 tile.
  const float qsc = (z == 0) ? QSCALE : 1.0f;
#pragma unroll
  for (int mt = 0; mt < 4; ++mt) {
    int m_base = m0 + wy * 64 + mt * 16 + quad * 4;
    int b = m_base >> 11, s_base = m_base & (SEQ - 1);
#pragma unroll
    for (int nt = 0; nt < 4; ++nt) {
      int n = n0 + wx * 64 + nt * 16 + l15;
      if (mode == 0) {
#pragma unroll
        for (int r = 0; r < 4; ++r)
          outF[(size_t)(m_base + r) * D_MODEL + n] = acc[mt][nt][r];
      } else {
        int h = n >> 6, dh = n & 63;
        if (z == 2) {  // V: transposed + key-permuted columns (see header)
          int p_base = (s_base & ~31) | (((s_base >> 2) & 3) << 3) |
                       (((s_base >> 4) & 1) << 2);
          ushort4 o;
          o.x = f2b(acc[mt][nt][0]); o.y = f2b(acc[mt][nt][1]);
          o.z = f2b(acc[mt][nt][2]); o.w = f2b(acc[mt][nt][3]);
          *(ushort4*)&outB[((size_t)(b * NHEAD + h) * DHEAD + dh) * SEQ + p_base] = o;
        } else {       // Q/K: RoPE via table, pair partner via lane shuffle
          int i = nt * 8 + (l15 >> 1);   // freq index, pair-uniform
          bool evn = !(l15 & 1);
#pragma unroll
          for (int r = 0; r < 4; ++r) {
            float v = acc[mt][nt][r];
            float pv = __shfl_xor(v, 1);
            float2 csn = tbl[(s_base + r) * 32 + i];
            v = v * csn.x + (evn ? -pv * csn.y : pv * csn.y);
            v *= qsc;
            outB[(((size_t)(b * NHEAD + h)) * SEQ + s_base + r) * DHEAD + dh] = f2b(v);
          }
        }
      }
    }
  }
}

// ---------------------------------------------------------------------------
// gemm_out: Wo projection, M=64 / BK=64 skeleton (R9 proven win: 512 blocks
// = 2 blocks/CU hides the vmcnt-drain barriers that the 1-block/CU M=128
// launch exposed; 166.0 -> 163.5 us). UNCHANGED.
// out = A @ W^T, fp32 row-major store.
// ---------------------------------------------------------------------------
__global__ __launch_bounds__(256)
void gemm_out(const ushort* __restrict__ A, const ushort* __restrict__ W,
              float* __restrict__ outF) {
  __shared__ ushort As[64 * 64];    // 8 KB
  __shared__ ushort Bs[128 * 64];   // 16 KB
  const int tid = threadIdx.x;
  const int lane = tid & 63;
  const int w = tid >> 6;           // wave owns col group w*32
  const int quad = lane >> 4, l15 = lane & 15;
  const int m0 = blockIdx.y * 64, n0 = blockIdx.x * 128;

  const int rl = tid >> 3;                // 0..31
  const int gsc = (tid & 7) ^ (rl & 7);   // pre-swizzled global chunk
  const ushort* Ag = A + (size_t)(m0 + rl) * D_MODEL + gsc * 8;
  const ushort* Wg = W + (size_t)(n0 + rl) * D_MODEL + gsc * 8;

  const int s0 = (quad ^ (l15 & 7)) * 8;  // kk=0; kk=1 is ^32 (ushorts)

  f32x4 acc[4][2];
#pragma unroll
  for (int i = 0; i < 4; ++i)
#pragma unroll
    for (int j = 0; j < 2; ++j) acc[i][j] = (f32x4){0.f, 0.f, 0.f, 0.f};

  for (int kt = 0; kt < D_MODEL / 64; ++kt) {
    if (kt) __syncthreads();
#pragma unroll
    for (int k4 = 0; k4 < 2; ++k4)   // A: 64 rows = 2 row-groups
      GLLDS16(Ag + kt * 64 + (size_t)(k4 * 32) * D_MODEL,
              &As[(size_t)tid * 8 + k4 * 2048]);
#pragma unroll
    for (int k4 = 0; k4 < 4; ++k4)   // W: 128 rows = 4 row-groups
      GLLDS16(Wg + kt * 64 + (size_t)(k4 * 32) * D_MODEL,
              &Bs[(size_t)tid * 8 + k4 * 2048]);
    __syncthreads();

#pragma unroll
    for (int kk = 0; kk < 2; ++kk) {
      const int sk = s0 ^ (kk * 32);
      bf16x8 af[4], bfr[2];
#pragma unroll
      for (int mt = 0; mt < 4; ++mt) {
        int row = mt * 16 + l15;
        af[mt] = *(const bf16x8*)&As[row * 64 + sk];
      }
#pragma unroll
      for (int nt = 0; nt < 2; ++nt) {
        int row = w * 32 + nt * 16 + l15;
        bfr[nt] = *(const bf16x8*)&Bs[row * 64 + sk];
      }
#pragma unroll
      for (int mt = 0; mt < 4; ++mt)
#pragma unroll
        for (int nt = 0; nt < 2; ++nt)
          acc[mt][nt] = __builtin_amdgcn_mfma_f32_16x16x32_bf16(
              af[mt], bfr[nt], acc[mt][nt], 0, 0, 0);
    }
  }

  // ---- epilogue: fp32 row-major. C/D: row = quad*4+r, col = l15.
#pragma unroll
  for (int mt = 0; mt < 4; ++mt) {
    int m_base = m0 + mt * 16 + quad * 4;
#pragma unroll
    for (int nt = 0; nt < 2; ++nt) {
      int n = n0 + w * 32 + nt * 16 + l15;
#pragma unroll
      for (int r = 0; r < 4; ++r)
        outF[(size_t)(m_base + r) * D_MODEL + n] = acc[mt][nt][r];
    }
  }
}

// ---------------------------------------------------------------------------
// bf16 MFMA causal flash attention -- R0 PROVEN FORM, setprio REVERTED
// (R12 isolated A/B: setprio = 164.5 vs 161.9 without; negative in the
// 4-wave-lockstep-block regime, consistent with m190 not m191). This
// structure survived R2/R4/R6/R7/R12 perturbations -- converged optimum.
// S^T = K.Q^T via mfma(A=K, B=Q): qrow in l15, keys in quad*4+r; exp2'd
// P packed to bf16 in registers feeds O^T = V^T.P^T directly (key-permuted
// Vt columns baked by the QKV gemm). Unpadded XOR LDS geometry
// (conflicts=0); register-prefetch staging; per-lane scalar row sums.
// Heads 8-15 walk qt reversed for CU balance. 1024 blocks, 4/CU, 16KB LDS.
// ---------------------------------------------------------------------------
__global__ __launch_bounds__(256)
void flash_mfma(const ushort* __restrict__ Q, const ushort* __restrict__ K,
                const ushort* __restrict__ Vt, ushort* __restrict__ O) {
  __shared__ ushort Ks[64 * 64];     // [key][dh], chunk-swizzled
  __shared__ ushort Vs[64 * 64];     // [dh][keypos], chunk-swizzled
  const int tid = threadIdx.x;
  const int lane = tid & 63, w = tid >> 6;
  const int quad = lane >> 4, l15 = lane & 15;
  const int h = blockIdx.y, b = blockIdx.z;
  const int qt = (h >= 8) ? (31 - blockIdx.x) : blockIdx.x;
  const int bh = b * NHEAD + h;

  // Q as B-operand (B frag layout == A frag layout): lane n=l15=qrow
  const int qrow = qt * 64 + w * 16 + l15;
  const ushort* Qrow = Q + ((size_t)bh * SEQ + qrow) * 64;
  bf16x8 aq0 = *(const bf16x8*)(Qrow + quad * 8);
  bf16x8 aq1 = *(const bf16x8*)(Qrow + 32 + quad * 8);

  // staging: thread owns rows rl and rl+32, LDS slot tid&7, global chunk XOR'd
  const int rl = tid >> 3;
  const int gsc = (tid & 7) ^ (rl & 7);  // (rl+32)&7 == rl&7
  const ushort* Kg0 = K + ((size_t)bh * SEQ + rl) * 64 + gsc * 8;
  const ushort* Kg1 = Kg0 + (size_t)32 * 64;
  const ushort* Vg0 = Vt + ((size_t)bh * 64 + rl) * SEQ + gsc * 8;
  const ushort* Vg1 = Vg0 + (size_t)32 * SEQ;

  // reader chunk slots (slot quad^(r&7) holds chunk quad; frag rows r&7==l15&7)
  const int sA = (quad ^ (l15 & 7)) * 8;  // dh/keypos 0..31
  const int sB = sA ^ 32;                 // dh/keypos 32..63

  float rsl = 0.f;       // per-lane row sum (lane's qrow)
  f32x4 accO[4];         // O^T dh-tiles: row=dh quad*4+r, col=l15=qrow
#pragma unroll
  for (int nt = 0; nt < 4; ++nt) accO[nt] = (f32x4){0.f, 0.f, 0.f, 0.f};

  float4 pk0 = *(const float4*)(Kg0);
  float4 pk1 = *(const float4*)(Kg1);
  float4 pv0 = *(const float4*)(Vg0);
  float4 pv1 = *(const float4*)(Vg1);

  for (int kt = 0; kt <= qt; ++kt) {
    __syncthreads();  // prior iter's LDS reads complete
    *(float4*)&Ks[tid * 8]        = pk0;
    *(float4*)&Ks[2048 + tid * 8] = pk1;
    *(float4*)&Vs[tid * 8]        = pv0;
    *(float4*)&Vs[2048 + tid * 8] = pv1;
    __syncthreads();
    if (kt < qt) {  // prefetch kt+1 into registers; overlaps all compute below
      pk0 = *(const float4*)(Kg0 + (size_t)(kt + 1) * 64 * 64);
      pk1 = *(const float4*)(Kg1 + (size_t)(kt + 1) * 64 * 64);
      pv0 = *(const float4*)(Vg0 + (kt + 1) * 64);
      pv1 = *(const float4*)(Vg1 + (kt + 1) * 64);
    }

    // ---- S^T = K . Q^T : C-tile nt holds keys nt*16+quad*4+r, qrow=l15
    f32x4 sc[4];
#pragma unroll
    for (int nt = 0; nt < 4; ++nt) {
      const ushort* kr = &Ks[(nt * 16 + l15) * 64];
      bf16x8 bk0 = *(const bf16x8*)(kr + sA);
      bf16x8 bk1 = *(const bf16x8*)(kr + sB);
      f32x4 zz = (f32x4){0.f, 0.f, 0.f, 0.f};
      zz = __builtin_amdgcn_mfma_f32_16x16x32_bf16(bk0, aq0, zz, 0, 0, 0);
      zz = __builtin_amdgcn_mfma_f32_16x16x32_bf16(bk1, aq1, zz, 0, 0, 0);
      sc[nt] = zz;
    }

    // ---- exp2 + causal mask + row-sum + pack P^T B-frags in registers
    const bool diag = (kt == qt);
    uint pk[8];
#pragma unroll
    for (int nt = 0; nt < 4; ++nt) {
      int kbase = kt * 64 + nt * 16 + quad * 4;
      ushort us[4];
#pragma unroll
      for (int r = 0; r < 4; ++r) {
        float p = __builtin_amdgcn_exp2f(sc[nt][r]);
        if (diag && kbase + r > qrow) p = 0.f;
        rsl += p;
        us[r] = f2b(p);
      }
      pk[nt * 2]     = (uint)us[0] | ((uint)us[1] << 16);
      pk[nt * 2 + 1] = (uint)us[2] | ((uint)us[3] << 16);
    }
    union { uint u[4]; bf16x8 v; } B0, B1;
    B0.u[0] = pk[0]; B0.u[1] = pk[1]; B0.u[2] = pk[2]; B0.u[3] = pk[3];
    B1.u[0] = pk[4]; B1.u[1] = pk[5]; B1.u[2] = pk[6]; B1.u[3] = pk[7];

    // ---- O^T += V^T . P^T  (A from LDS, B straight from registers)
#pragma unroll
    for (int nt = 0; nt < 4; ++nt) {
      const ushort* vr = &Vs[(nt * 16 + l15) * 64];
      bf16x8 av0 = *(const bf16x8*)(vr + sA);
      bf16x8 av1 = *(const bf16x8*)(vr + sB);
      accO[nt] = __builtin_amdgcn_mfma_f32_16x16x32_bf16(av0, B0.v, accO[nt], 0, 0, 0);
      accO[nt] = __builtin_amdgcn_mfma_f32_16x16x32_bf16(av1, B1.v, accO[nt], 0, 0, 0);
    }
  }

  // ---- row-sum reduction across the 4 quads (lane's qrow fixed = l15)
  rsl += __shfl_xor(rsl, 16);
  rsl += __shfl_xor(rsl, 32);
  float invl = 1.f / rsl;

  // ---- epilogue: attn_out bf16, (B,S,H*Dh); lane writes 4 ushort4 runs
  size_t base = ((size_t)(b * SEQ + qrow)) * D_MODEL + h * 64;
#pragma unroll
  for (int nt = 0; nt < 4; ++nt) {
    ushort4 o;
    o.x = f2b(accO[nt][0] * invl);
    o.y = f2b(accO[nt][1] * invl);
    o.z = f2b(accO[nt][2] * invl);
    o.w = f2b(accO[nt][3] * invl);
    *(ushort4*)&O[base + nt * 16 + quad * 4] = o;
  }
}

// ---------------------------------------------------------------------------
extern "C" void kernel_launch(void* const* d_in, const int* in_sizes, int n_in,
                              void* d_out, int out_size, void* d_ws, size_t ws_size,
                              hipStream_t stream) {
  const float* X  = (const float*)d_in[0];
  const float* Wq = (const float*)d_in[1];
  const float* Wk = (const float*)d_in[2];
  const float* Wv = (const float*)d_in[3];
  const float* Wo = (const float*)d_in[4];
  float* out = (float*)d_out;

  ushort* Xb  = (ushort*)d_ws;
  ushort* Wqb = Xb  + (size_t)MTOT * D_MODEL;
  ushort* Wkb = Wqb + (size_t)D_MODEL * D_MODEL;
  ushort* Wvb = Wkb + (size_t)D_MODEL * D_MODEL;
  ushort* Wob = Wvb + (size_t)D_MODEL * D_MODEL;
  ushort* Qw  = Wob + (size_t)D_MODEL * D_MODEL;
  ushort* Kw  = Qw  + (size_t)MTOT * D_MODEL;
  ushort* Vtw = Kw  + (size_t)MTOT * D_MODEL;  // (B,H,Dh,S) key-permuted
  ushort* At  = Vtw + (size_t)MTOT * D_MODEL;
  float2* tbl = (float2*)(At + (size_t)MTOT * D_MODEL);  // 512 KB

  prep<<<8448, 256, 0, stream>>>(X, Wq, Wk, Wv, Wo, Xb, Wqb, Wkb, Wvb, Wob, tbl);

  // QKV projection: M=128 tile (R10: M=64 regressed via L2-miss W re-fetch);
  // RoPE fused (table) on Q/K, Q pre-scaled; V transposed+permuted
  gemm_bf16<<<dim3(D_MODEL / 128, MTOT / 128, 3), 256, 0, stream>>>(
      Xb, Wqb, Wkb, Wvb, tbl, nullptr, Qw, Kw, Vtw, 1);

  flash_mfma<<<dim3(SEQ / 64, NHEAD, BATCH), 256, 0, stream>>>(Qw, Kw, Vtw, At);

  // Wo projection: M=64 tile -> 512 blocks = 2 blocks/CU (drain-hiding)
  gemm_out<<<dim3(D_MODEL / 128, MTOT / 64), 256, 0, stream>>>(At, Wob, out);
}